// Round 3
// baseline (115.307 us; speedup 1.0000x reference)
//
#include <hip/hip_runtime.h>
#include <hip/hip_bf16.h>
#include <math.h>

#define XDIM 2048
#define OW   2033        // 2048 - 16 + 1
#define TR   32          // out rows per block tile
#define TC   256         // out cols per block tile
#define XW   272         // staged pair-columns per image row (TC + 16)
#define CH   8           // rows per streaming chunk
#define NCHUNK 6         // ceil(47/8)
#define NG   24          // 4 channels * 6 chunks

typedef __bf16 bf16x8 __attribute__((ext_vector_type(8)));
typedef float  f32x16 __attribute__((ext_vector_type(16)));

union U128 { uint4 u; bf16x8 v; };

__device__ __forceinline__ unsigned short bfbits(float f) {
    return __builtin_bit_cast(unsigned short, __float2bfloat16(f));
}
// pair word: low16 = bf16(x^2) (plane p=0, weight w), high16 = bf16(x) (plane p=1, weight -2wk)
__device__ __forceinline__ unsigned int packx(float f) {
    return ((unsigned int)bfbits(f) << 16) | (unsigned int)bfbits(f * f);
}

__global__ __launch_bounds__(256) void psnr_mfma_kernel(
    const float* __restrict__ x,
    const float* __restrict__ kern,
    float* __restrict__ out)
{
    // Overlapped pairs: bufT[b][r][c] = (P[c], P[c+1]) -> any 4-word window
    // [c..c+3] = two aligned ds_read_b64 at T[c], T[c+2].
    __shared__ __align__(16) uint2 bufT[3][CH][XW];          // 52.2 KB
    __shared__ __align__(16) unsigned int wt[4][17][20];     // 5.44 KB
    __shared__ float skkArr[4];

    const int tid  = threadIdx.x;
    const int lane = tid & 63;
    const int wv   = tid >> 6;         // wave 0..3
    const int nn   = lane & 31;        // m for A-frags, n for B-frags
    const int hf   = lane >> 5;        // k-block half

    // ---------------- weight tables + Skk (once per block) ----------------
    {
        float k0 = kern[tid], k1 = kern[256 + tid], k2 = kern[512 + tid], k3 = kern[768 + tid];
        float a  = k3 * (1.0f / 255.0f);
        float om = 1.0f - a;
        float w  = om * om;
        int i = tid >> 4, j = tid & 15;
        unsigned int wlo = (unsigned int)bfbits(w);
        wt[0][i][j] = ((unsigned int)bfbits(-2.0f * w * k0) << 16) | wlo;
        wt[1][i][j] = ((unsigned int)bfbits(-2.0f * w * k1) << 16) | wlo;
        wt[2][i][j] = ((unsigned int)bfbits(-2.0f * w * k2) << 16) | wlo;
        wt[3][i][j] = ((unsigned int)bfbits(-2.0f * w * k3) << 16) | wlo;
        if (tid < 80) {                       // zero row 16 of each channel table
            int c = tid / 20, wd = tid % 20;
            wt[c][16][wd] = 0u;
        }
        float4* red = reinterpret_cast<float4*>(&bufT[0][0][0]);   // scratch before pipeline
        red[tid] = make_float4(w*k0*k0, w*k1*k1, w*k2*k2, w*k3*k3);
        __syncthreads();
        #pragma unroll
        for (int s = 128; s > 0; s >>= 1) {
            if (tid < s) {
                float4 o = red[tid + s], m = red[tid];
                m.x += o.x; m.y += o.y; m.z += o.z; m.w += o.w;
                red[tid] = m;
            }
            __syncthreads();
        }
        if (tid == 0) {
            float4 r0v = red[0];
            skkArr[0] = r0v.x; skkArr[1] = r0v.y; skkArr[2] = r0v.z; skkArr[3] = r0v.w;
        }
        __syncthreads();
    }

    const int r0 = blockIdx.y * TR;
    const int c0 = blockIdx.x * TC;

    // -------- streaming stage helpers (544 float4-items per chunk) --------
    // item idx -> row lr = idx/68, pair-col q4 = (idx%68)*4; loads x[gr][gc..gc+4]
    float4 sv4[2][3];
    float  sv1[2][3];

    auto stage_issue = [&](int g, int rs) {
        int c  = g % NCHUNK;
        int ch = g / NCHUNK;
        const float* __restrict__ xc = x + (size_t)ch * XDIM * XDIM;
        #pragma unroll
        for (int t = 0; t < 3; ++t) {
            int idx = tid + 256 * t;
            if (idx < CH * 68) {
                int lr = idx / 68;
                int q4 = (idx - lr * 68) * 4;
                int gr = r0 + c * CH + lr; if (gr > XDIM - 1) gr = XDIM - 1;
                int gc = c0 + q4;
                const float* rp = xc + (size_t)gr * XDIM;
                float4 v;
                if (gc + 3 <= XDIM - 1) {
                    v = *reinterpret_cast<const float4*>(rp + gc);
                } else {
                    int e0 = gc     < XDIM ? gc     : XDIM - 1;
                    int e1 = gc + 1 < XDIM ? gc + 1 : XDIM - 1;
                    int e2 = gc + 2 < XDIM ? gc + 2 : XDIM - 1;
                    int e3 = gc + 3 < XDIM ? gc + 3 : XDIM - 1;
                    v = make_float4(rp[e0], rp[e1], rp[e2], rp[e3]);
                }
                int g4 = gc + 4 < XDIM ? gc + 4 : XDIM - 1;
                sv4[rs][t] = v;
                sv1[rs][t] = rp[g4];
            }
        }
    };

    auto stage_write = [&](int g, int rs) {
        int b = g % 3;
        #pragma unroll
        for (int t = 0; t < 3; ++t) {
            int idx = tid + 256 * t;
            if (idx < CH * 68) {
                int lr = idx / 68;
                int q4 = (idx - lr * 68) * 4;
                float4 v = sv4[rs][t];
                unsigned int P0 = packx(v.x), P1 = packx(v.y), P2 = packx(v.z),
                             P3 = packx(v.w), P4 = packx(sv1[rs][t]);
                uint4* dst = reinterpret_cast<uint4*>(&bufT[b][lr][q4]);
                dst[0] = make_uint4(P0, P1, P1, P2);
                dst[1] = make_uint4(P2, P3, P3, P4);
            }
        }
    };

    // -------- pipeline prologue: chunks 0,1 staged; chunk 2 in flight --------
    stage_issue(0, 0);
    stage_issue(1, 1);
    stage_write(0, 0);
    stage_issue(2, 0);
    stage_write(1, 1);
    __syncthreads();

    f32x16 acc0, acc1, psum0, psum1;
    #pragma unroll
    for (int q = 0; q < 16; ++q) { psum0[q] = 0.0f; psum1[q] = 0.0f; }

    const int xbase = nn + 4 * hf + (wv << 6);

    for (int g = 0; g < NG; ++g) {
        const int c  = g % NCHUNK;
        const int ch = g / NCHUNK;

        if (g + 2 < NG) stage_write(g + 2, g & 1);
        if (g + 3 < NG) stage_issue(g + 3, (g + 1) & 1);

        if (c == 0) {
            #pragma unroll
            for (int q = 0; q < 16; ++q) { acc0[q] = 0.0f; acc1[q] = 0.0f; }
        }

        const uint2* __restrict__ bp = &bufT[g % 3][0][0];
        const unsigned int* __restrict__ wch = &wt[ch][0][0];

        #pragma unroll
        for (int lr = 0; lr < CH; ++lr) {
            int ip = c * CH + lr;
            if (ip < 47) {
                unsigned int d = (unsigned int)(ip - nn);
                unsigned int wrow = (d > 15u) ? 16u : d;
                U128 alo, ahi;
                alo.u = *reinterpret_cast<const uint4*>(wch + wrow * 20 + hf * 4);
                ahi.u = *reinterpret_cast<const uint4*>(wch + wrow * 20 + 8 + hf * 4);

                int xb = lr * XW + xbase;
                U128 blo0, bhi0, blo1, bhi1;
                { uint2 a0 = bp[xb],      a1 = bp[xb + 2];  blo0.u = make_uint4(a0.x, a0.y, a1.x, a1.y); }
                { uint2 a0 = bp[xb + 8],  a1 = bp[xb + 10]; bhi0.u = make_uint4(a0.x, a0.y, a1.x, a1.y); }
                { uint2 a0 = bp[xb + 32], a1 = bp[xb + 34]; blo1.u = make_uint4(a0.x, a0.y, a1.x, a1.y); }
                { uint2 a0 = bp[xb + 40], a1 = bp[xb + 42]; bhi1.u = make_uint4(a0.x, a0.y, a1.x, a1.y); }

                acc0 = __builtin_amdgcn_mfma_f32_32x32x16_bf16(alo.v, blo0.v, acc0, 0, 0, 0);
                acc0 = __builtin_amdgcn_mfma_f32_32x32x16_bf16(ahi.v, bhi0.v, acc0, 0, 0, 0);
                acc1 = __builtin_amdgcn_mfma_f32_32x32x16_bf16(alo.v, blo1.v, acc1, 0, 0, 0);
                acc1 = __builtin_amdgcn_mfma_f32_32x32x16_bf16(ahi.v, bhi1.v, acc1, 0, 0, 0);
            }
        }

        if (c == NCHUNK - 1) {            // channel epilogue
            float sk = skkArr[ch];
            #pragma unroll
            for (int q = 0; q < 16; ++q) {
                float m0 = (acc0[q] + sk) * (1.0f / 256.0f);
                float m1 = (acc1[q] + sk) * (1.0f / 256.0f);
                psum0[q] += log10f(m0);
                psum1[q] += log10f(m1);
            }
        }

        __syncthreads();
    }

    // ---------------- store: psnr = 20log10(255) - 2.5 * sum_c log10(mse_c) ----------------
    const float BASE = 48.130803608679344f;
    const int col0 = c0 + (wv << 6) + nn;
    const int col1 = col0 + 32;
    #pragma unroll
    for (int q = 0; q < 16; ++q) {
        int row = r0 + (q & 3) + ((q >> 2) << 3) + (hf << 2);
        if (row < OW) {
            float* orow = out + (size_t)row * OW;
            if (col0 < OW) orow[col0] = BASE - 2.5f * psum0[q];
            if (col1 < OW) orow[col1] = BASE - 2.5f * psum1[q];
        }
    }
}

extern "C" void kernel_launch(void* const* d_in, const int* in_sizes, int n_in,
                              void* d_out, int out_size, void* d_ws, size_t ws_size,
                              hipStream_t stream) {
    (void)in_sizes; (void)n_in; (void)d_ws; (void)ws_size; (void)out_size;
    const float* x    = (const float*)d_in[0];
    const float* kern = (const float*)d_in[1];
    float* out        = (float*)d_out;

    dim3 grid(XDIM / TC, (OW + TR - 1) / TR);   // 8 x 64 = 512 blocks
    psnr_mfma_kernel<<<grid, 256, 0, stream>>>(x, kern, out);
}

// Round 4
// 86.449 us; speedup vs baseline: 1.3338x; 1.3338x over previous
//
#include <hip/hip_runtime.h>
#include <hip/hip_bf16.h>
#include <math.h>

#define XDIM 2048
#define OW   2033        // 2048 - 16 + 1
#define TR   32          // out rows per block tile
#define TC   256         // out cols per block tile
#define XW   272         // staged pair-columns per image row (TC + 16)
#define CH   8           // rows per streaming chunk
#define NCHUNK 6         // ceil(47/8)
#define NG   24          // 4 channels * 6 chunks

typedef __bf16 bf16x8 __attribute__((ext_vector_type(8)));
typedef float  f32x16 __attribute__((ext_vector_type(16)));

union U128 { uint4 u; bf16x8 v; };

__device__ __forceinline__ unsigned short bfbits(float f) {
    return __builtin_bit_cast(unsigned short, __float2bfloat16(f));
}
// pair word: low16 = bf16(x^2) (plane p=0, weight w), high16 = bf16(x) (plane p=1, weight -2wk)
__device__ __forceinline__ unsigned int packx(float f) {
    return ((unsigned int)bfbits(f) << 16) | (unsigned int)bfbits(f * f);
}

__global__ __launch_bounds__(256) void psnr_mfma_kernel(
    const float* __restrict__ x,
    const float* __restrict__ kern,
    float* __restrict__ out)
{
    // Overlapped pairs: bufT[b][r][c] = (P[c], P[c+1]) -> any 4-word window
    // [c..c+3] = two aligned 8B reads at T[c], T[c+2] (mergeable ds_read2_b64).
    __shared__ __align__(16) uint2 bufT[3][CH][XW];          // 52.2 KB
    __shared__ __align__(16) unsigned int wt[4][17][20];     // 5.44 KB
    __shared__ float skkArr[4];

    const int tid  = threadIdx.x;
    const int lane = tid & 63;
    const int wv   = tid >> 6;         // wave 0..3
    const int nn   = lane & 31;        // m for A-frags, n for B-frags
    const int hf   = lane >> 5;        // k-block half

    // ---------------- weight tables + Skk (once per block) ----------------
    {
        float k0 = kern[tid], k1 = kern[256 + tid], k2 = kern[512 + tid], k3 = kern[768 + tid];
        float a  = k3 * (1.0f / 255.0f);
        float om = 1.0f - a;
        float w  = om * om;
        int i = tid >> 4, j = tid & 15;
        unsigned int wlo = (unsigned int)bfbits(w);
        wt[0][i][j] = ((unsigned int)bfbits(-2.0f * w * k0) << 16) | wlo;
        wt[1][i][j] = ((unsigned int)bfbits(-2.0f * w * k1) << 16) | wlo;
        wt[2][i][j] = ((unsigned int)bfbits(-2.0f * w * k2) << 16) | wlo;
        wt[3][i][j] = ((unsigned int)bfbits(-2.0f * w * k3) << 16) | wlo;
        if (tid < 80) {                       // zero row 16 of each channel table
            int c = tid / 20, wd = tid % 20;
            wt[c][16][wd] = 0u;
        }
        float4* red = reinterpret_cast<float4*>(&bufT[0][0][0]);   // scratch before pipeline
        red[tid] = make_float4(w*k0*k0, w*k1*k1, w*k2*k2, w*k3*k3);
        __syncthreads();
        #pragma unroll
        for (int s = 128; s > 0; s >>= 1) {
            if (tid < s) {
                float4 o = red[tid + s], m = red[tid];
                m.x += o.x; m.y += o.y; m.z += o.z; m.w += o.w;
                red[tid] = m;
            }
            __syncthreads();
        }
        if (tid == 0) {
            float4 r0v = red[0];
            skkArr[0] = r0v.x; skkArr[1] = r0v.y; skkArr[2] = r0v.z; skkArr[3] = r0v.w;
        }
        __syncthreads();
    }

    const int r0 = blockIdx.y * TR;
    const int c0 = blockIdx.x * TC;

    // -------- streaming stage helpers: 544 items/chunk, item = 4 pair-cols --------
    // STATIC register sets (named, never runtime-indexed) -> no scratch.
    float4 rA4[3], rB4[3];
    float  rA1[3], rB1[3];

    auto stage_issue = [&](int g, float4 (&v4)[3], float (&v1)[3]) {
        int c  = g % NCHUNK;
        int ch = g / NCHUNK;
        const float* __restrict__ xc = x + (size_t)ch * XDIM * XDIM;
        #pragma unroll
        for (int t = 0; t < 3; ++t) {
            int idx = tid + 256 * t;
            if (idx < CH * 68) {
                int lr = idx / 68;
                int q4 = (idx - lr * 68) * 4;
                int gr = r0 + c * CH + lr; if (gr > XDIM - 1) gr = XDIM - 1;
                int gc = c0 + q4;
                const float* rp = xc + (size_t)gr * XDIM;
                float4 v;
                if (gc + 3 <= XDIM - 1) {
                    v = *reinterpret_cast<const float4*>(rp + gc);
                } else {
                    int e0 = gc     < XDIM ? gc     : XDIM - 1;
                    int e1 = gc + 1 < XDIM ? gc + 1 : XDIM - 1;
                    int e2 = gc + 2 < XDIM ? gc + 2 : XDIM - 1;
                    int e3 = gc + 3 < XDIM ? gc + 3 : XDIM - 1;
                    v = make_float4(rp[e0], rp[e1], rp[e2], rp[e3]);
                }
                int g4 = gc + 4 < XDIM ? gc + 4 : XDIM - 1;
                v4[t] = v;
                v1[t] = rp[g4];
            }
        }
    };

    auto stage_write = [&](int g, float4 (&v4)[3], float (&v1)[3]) {
        int b = g % 3;
        #pragma unroll
        for (int t = 0; t < 3; ++t) {
            int idx = tid + 256 * t;
            if (idx < CH * 68) {
                int lr = idx / 68;
                int q4 = (idx - lr * 68) * 4;
                float4 v = v4[t];
                unsigned int P0 = packx(v.x), P1 = packx(v.y), P2 = packx(v.z),
                             P3 = packx(v.w), P4 = packx(v1[t]);
                uint4* dst = reinterpret_cast<uint4*>(&bufT[b][lr][q4]);
                dst[0] = make_uint4(P0, P1, P1, P2);
                dst[1] = make_uint4(P2, P3, P3, P4);
            }
        }
    };

    f32x16 acc0, acc1, psum0, psum1;
    #pragma unroll
    for (int q = 0; q < 16; ++q) { psum0[q] = 0.0f; psum1[q] = 0.0f; }

    const int xbase = nn + 4 * hf + (wv << 6);

    auto compute = [&](int g) {
        const int c  = g % NCHUNK;
        const int ch = g / NCHUNK;
        if (c == 0) {
            #pragma unroll
            for (int q = 0; q < 16; ++q) { acc0[q] = 0.0f; acc1[q] = 0.0f; }
        }
        const uint2* __restrict__ bp = &bufT[g % 3][0][0];
        const unsigned int* __restrict__ wch = &wt[ch][0][0];

        #pragma unroll
        for (int lr = 0; lr < CH; ++lr) {
            int ip = c * CH + lr;
            if (ip < 47) {
                unsigned int d = (unsigned int)(ip - nn);
                unsigned int wrow = (d > 15u) ? 16u : d;
                U128 alo, ahi;
                alo.u = *reinterpret_cast<const uint4*>(wch + wrow * 20 + hf * 4);
                ahi.u = *reinterpret_cast<const uint4*>(wch + wrow * 20 + 8 + hf * 4);

                int xb = lr * XW + xbase;
                U128 blo0, bhi0, blo1, bhi1;
                { uint2 a0 = bp[xb],      a1 = bp[xb + 2];  blo0.u = make_uint4(a0.x, a0.y, a1.x, a1.y); }
                { uint2 a0 = bp[xb + 8],  a1 = bp[xb + 10]; bhi0.u = make_uint4(a0.x, a0.y, a1.x, a1.y); }
                { uint2 a0 = bp[xb + 32], a1 = bp[xb + 34]; blo1.u = make_uint4(a0.x, a0.y, a1.x, a1.y); }
                { uint2 a0 = bp[xb + 40], a1 = bp[xb + 42]; bhi1.u = make_uint4(a0.x, a0.y, a1.x, a1.y); }

                acc0 = __builtin_amdgcn_mfma_f32_32x32x16_bf16(alo.v, blo0.v, acc0, 0, 0, 0);
                acc0 = __builtin_amdgcn_mfma_f32_32x32x16_bf16(ahi.v, bhi0.v, acc0, 0, 0, 0);
                acc1 = __builtin_amdgcn_mfma_f32_32x32x16_bf16(alo.v, blo1.v, acc1, 0, 0, 0);
                acc1 = __builtin_amdgcn_mfma_f32_32x32x16_bf16(ahi.v, bhi1.v, acc1, 0, 0, 0);
            }
        }

        if (c == NCHUNK - 1) {            // channel epilogue
            float sk = skkArr[ch];
            #pragma unroll
            for (int q = 0; q < 16; ++q) {
                float m0 = (acc0[q] + sk) * (1.0f / 256.0f);
                float m1 = (acc1[q] + sk) * (1.0f / 256.0f);
                psum0[q] += log10f(m0);
                psum1[q] += log10f(m1);
            }
        }
    };

    // -------- prologue: buf0 written; chunks 1 (rB) and 2 (rA) in flight --------
    stage_issue(0, rA4, rA1);
    stage_write(0, rA4, rA1);
    stage_issue(1, rB4, rB1);
    stage_issue(2, rA4, rA1);
    __syncthreads();

    // -------- main loop, 2-unrolled so register-set choice is static --------
    for (int g = 0; g < NG; g += 2) {
        // even section: compute g; rB holds chunk g+1
        if (g + 1 < NG) stage_write(g + 1, rB4, rB1);
        if (g + 3 < NG) stage_issue(g + 3, rB4, rB1);
        __syncthreads();
        compute(g);

        // odd section: compute g+1; rA holds chunk g+2
        if (g + 2 < NG) stage_write(g + 2, rA4, rA1);
        if (g + 4 < NG) stage_issue(g + 4, rA4, rA1);
        __syncthreads();
        if (g + 1 < NG) compute(g + 1);
    }

    // ---------------- store: psnr = 20log10(255) - 2.5 * sum_c log10(mse_c) ----------------
    const float BASE = 48.130803608679344f;
    const int col0 = c0 + (wv << 6) + nn;
    const int col1 = col0 + 32;
    #pragma unroll
    for (int q = 0; q < 16; ++q) {
        int row = r0 + (q & 3) + ((q >> 2) << 3) + (hf << 2);
        if (row < OW) {
            float* orow = out + (size_t)row * OW;
            if (col0 < OW) orow[col0] = BASE - 2.5f * psum0[q];
            if (col1 < OW) orow[col1] = BASE - 2.5f * psum1[q];
        }
    }
}

extern "C" void kernel_launch(void* const* d_in, const int* in_sizes, int n_in,
                              void* d_out, int out_size, void* d_ws, size_t ws_size,
                              hipStream_t stream) {
    (void)in_sizes; (void)n_in; (void)d_ws; (void)ws_size; (void)out_size;
    const float* x    = (const float*)d_in[0];
    const float* kern = (const float*)d_in[1];
    float* out        = (float*)d_out;

    dim3 grid(XDIM / TC, (OW + TR - 1) / TR);   // 8 x 64 = 512 blocks
    psnr_mfma_kernel<<<grid, 256, 0, stream>>>(x, kern, out);
}